// Round 3
// baseline (333.627 us; speedup 1.0000x reference)
//
#include <hip/hip_runtime.h>
#include <hip/hip_bf16.h>
#include <stdint.h>

typedef unsigned short u16;
typedef __attribute__((ext_vector_type(8))) short bf16x8;
typedef __attribute__((ext_vector_type(4))) float f32x4;
typedef __attribute__((ext_vector_type(4))) uint32_t u32x4;

__device__ inline u16 f2bf(float f) {
  union { float f; uint32_t u; } v; v.f = f;
  uint32_t u = v.u;
  u += 0x7FFFu + ((u >> 16) & 1u);
  return (u16)(u >> 16);
}
__device__ inline uint32_t pkbf(float a, float b) {
  union { __hip_bfloat162 h; uint32_t u; } c;
  c.h = __float22bfloat162_rn(float2{a, b});
  return c.u;
}
__device__ inline float bf2f(u16 h) {
  union { uint32_t u; float f; } v; v.u = (uint32_t)h << 16; return v.f;
}
__device__ inline void gl_lds16(const void* g, void* s) {
  __builtin_amdgcn_global_load_lds(
      (const __attribute__((address_space(1))) void*)(uintptr_t)(g),
      (__attribute__((address_space(3))) void*)(uint32_t)(uintptr_t)(s),
      16, 0, 0);
}

// ---- prolog: eig partial means (0..63) + x transpose (64..319)
//      + VT weight fold (320..703) + cvec (704) + U bf16 dual-copy (705..2752)
// U-pass: 128x128 tiles. Ubf written straight from registers (16-B stores,
// 256-B islands). UTr via pair-packed u32 LDS [n][m-pair] (pad 72), read as
// conflict-free b128, written as 16-lane 256-B row islands.
__global__ __launch_bounds__(256) void k_pre(
    const float* __restrict__ eig, const float* __restrict__ x,
    const float* __restrict__ U,
    const float* __restrict__ WS, const float* __restrict__ WM,
    const float* __restrict__ Ww, const float* __restrict__ bS,
    const float* __restrict__ bM, const float* __restrict__ bw,
    float* __restrict__ part, u16* __restrict__ xT,
    u16* __restrict__ VT, float* __restrict__ cvec,
    u16* __restrict__ Ubf, u16* __restrict__ UTr) {
  const int bid = blockIdx.x, t = threadIdx.x;
  __shared__ union {
    float red[256];
    uint32_t L[64][33];
    uint32_t Lp[128 * 72];
  } sh;
  if (bid < 64) {
    const int b = bid >> 5, chunk = bid & 31;
    const int d = t & 127, half = t >> 7;
    const float* p = eig + ((long)b * 4096 + chunk * 128 + half) * 128 + d;
    float s = 0.0f;
    for (int i = 0; i < 64; i++) s += p[(long)i * 256];
    sh.red[t] = s;
    __syncthreads();
    if (t < 128) part[((long)b * 32 + chunk) * 128 + d] = sh.red[t] + sh.red[t + 128];
    return;
  }
  if (bid < 320) {
    // x fp32 [4096][128] -> xT bf16 [128][4096], 64x64 tiles
    const int q = bid - 64;
    const int b = q >> 7, rem = q & 127;
    const int tr = rem & 63, tc = rem >> 6;
    const float* I = x + (long)b * 524288;
    u16* O = xT + (long)b * 524288;
    const int r = t >> 2, cq = (t & 3) * 4;
    const float* src = I + (long)(tr * 64 + r) * 128 + tc * 64;
#pragma unroll
    for (int i = 0; i < 4; i++) {
      const float4 f = *(const float4*)(src + cq + 16 * i);
      const int c = cq + 16 * i;
      sh.L[r][(c >> 1)]     = pkbf(f.x, f.y);
      sh.L[r][(c >> 1) + 1] = pkbf(f.z, f.w);
    }
    __syncthreads();
    const int r0 = (t & 7) * 8;
#pragma unroll
    for (int p = 0; p < 2; p++) {
      const int c = (t >> 3) + 32 * p;
      uint32_t w[4];
#pragma unroll
      for (int i = 0; i < 4; i++) {
        const uint32_t w0 = sh.L[r0 + 2 * i][c >> 1];
        const uint32_t w1 = sh.L[r0 + 2 * i + 1][c >> 1];
        const u16 v0 = (c & 1) ? (u16)(w0 >> 16) : (u16)(w0 & 0xffff);
        const u16 v1 = (c & 1) ? (u16)(w1 >> 16) : (u16)(w1 & 0xffff);
        w[i] = (uint32_t)v0 | ((uint32_t)v1 << 16);
      }
      u32x4* dst = (u32x4*)(O + (long)(tc * 64 + c) * 4096 + tr * 64 + r0);
      *dst = u32x4{w[0], w[1], w[2], w[3]};
    }
    return;
  }
  if (bid < 704) {
    // VT[e][f*128+d] = (F_f @ Ww)[d][e]; 2 q per block
    const int q = (bid - 320) * 2 + (t >> 7);
    const int e = t & 127;
    const int f = q >> 7, d = q & 127;
    const float* Frow = (f == 0) ? (WS + d * 128) : (WM + ((long)(f - 1) * 128 + d) * 128);
    float s = 0.0f;
    for (int k = 0; k < 128; k++) s += Frow[k] * Ww[k * 128 + e];
    VT[(long)e * 768 + f * 128 + d] = f2bf(s);
    return;
  }
  if (bid == 704) {
    // cvec
    if (t >= 128) return;
    float s = bw[t];
    for (int k = 0; k < 128; k++) {
      float tv = bS[k];
#pragma unroll
      for (int j = 0; j < 5; j++) tv += bM[j * 128 + k];
      s += tv * Ww[k * 128 + t];
    }
    cvec[t] = s;
    return;
  }
  // U fp32 [4096][4096] -> Ubf (cast) + UTr (transpose), 128x128 tiles
  {
    const int q = bid - 705;          // 0..2047
    const int b = q >> 10;            // batch
    const int rem = q & 1023;
    const int ti = rem & 31;          // m-tile
    const int tj = rem >> 5;          // n-tile
    const long ubase = (long)b * 16777216 + (long)(ti * 128) * 4096 + tj * 128;
    const float* Iu = U + ubase;
    u16* Os = Ubf + ubase;
    u16* Ot = UTr + (long)b * 16777216 + (long)(tj * 128) * 4096 + ti * 128;
    const int a = t >> 2;             // row-pair 0..63 (rows 2a, 2a+1)
    const int c0 = (t & 3) * 32;      // col offset
    const float* r0 = Iu + (long)(2 * a) * 4096 + c0;
    const float* r1 = r0 + 4096;
    float4 f0[8], f1[8];
#pragma unroll
    for (int i = 0; i < 8; i++) {
      f0[i] = *(const float4*)(r0 + 4 * i);
      f1[i] = *(const float4*)(r1 + 4 * i);
    }
    // Ubf straight-cast: 4x16-B per row, threads t..t+3 contiguous 256 B
    u16* d0 = Os + (long)(2 * a) * 4096 + c0;
    u16* d1 = d0 + 4096;
#pragma unroll
    for (int i = 0; i < 4; i++) {
      *(u32x4*)(d0 + 8 * i) = u32x4{pkbf(f0[2*i].x, f0[2*i].y), pkbf(f0[2*i].z, f0[2*i].w),
                                    pkbf(f0[2*i+1].x, f0[2*i+1].y), pkbf(f0[2*i+1].z, f0[2*i+1].w)};
      *(u32x4*)(d1 + 8 * i) = u32x4{pkbf(f1[2*i].x, f1[2*i].y), pkbf(f1[2*i].z, f1[2*i].w),
                                    pkbf(f1[2*i+1].x, f1[2*i+1].y), pkbf(f1[2*i+1].z, f1[2*i+1].w)};
    }
    // LDS pair-pack: Lp[n][a] = (bf(row2a), bf(row2a+1)) at column n
#pragma unroll
    for (int i = 0; i < 8; i++) {
      const int n = c0 + 4 * i;
      sh.Lp[(n + 0) * 72 + a] = pkbf(f0[i].x, f1[i].x);
      sh.Lp[(n + 1) * 72 + a] = pkbf(f0[i].y, f1[i].y);
      sh.Lp[(n + 2) * 72 + a] = pkbf(f0[i].z, f1[i].z);
      sh.Lp[(n + 3) * 72 + a] = pkbf(f0[i].w, f1[i].w);
    }
    __syncthreads();
    // UTr: 16 lanes cover one n-row's 128 m (256 B); 16 rows/pass, 8 passes
    const int g = t >> 4;             // row-group 0..15
    const int j = t & 15;             // 16-B chunk in row
#pragma unroll
    for (int p = 0; p < 8; p++) {
      const int n = p * 16 + g;
      const u32x4 v = *(const u32x4*)&sh.Lp[n * 72 + j * 4];
      *(u32x4*)(Ot + (long)n * 4096 + j * 8) = v;
    }
  }
}

// ======================================================================
// Unified GEMM template:
//  - A,B bf16 via global_load_lds, 128x32 tiles (64-B rows), LDS linear.
//  - Source columns pre-swizzled c_phys = c_log ^ ((row>>1)&3) (16-B units);
//    reads apply the same XOR -> <=2-way bank conflict (free).
//  - 4-buffer rotation, counted s_waitcnt vmcnt(8): tile t+1 guaranteed,
//    tiles t+2,t+3 in flight -> 2+ compute phases of latency cover.
//    64 KB LDS -> 2 blocks/CU (grid <= 2.06/CU anyway).
// ======================================================================

// ---- GEMM1: xs[ks][b][n][d] = partial sum_m U[m][n] * x[m][d]
// A = xT bf16 [d][m]; B = UTr bf16 [n][m]. tn==32 blocks do pooled coeffs.
__global__ __launch_bounds__(256) void k_gemm1(
    const u16* __restrict__ xT, const u16* __restrict__ UTr,
    const float* __restrict__ part,
    const float* __restrict__ Wa, const float* __restrict__ ba,
    const float* __restrict__ Wb, const float* __restrict__ bb_,
    const float* __restrict__ Ws, const float* __restrict__ bs,
    float* __restrict__ xs, float* __restrict__ coeff) {
  const int tn = blockIdx.x, ks = blockIdx.y, bb = blockIdx.z;
  const int tid = threadIdx.x;
  __shared__ float sd[128];
  __shared__ __align__(16) u16 As[4 * 4096];
  __shared__ __align__(16) u16 Bs[4 * 4096];
  if (tn == 32) {
    if (ks != 0) return;
    if (tid < 128) {
      float s = 0.0f;
      for (int c = 0; c < 32; c++) s += part[((long)bb * 32 + c) * 128 + tid];
      sd[tid] = s * (1.0f / 4096.0f);
    }
    __syncthreads();
    if (tid >= 15) return;
    const int kind = tid / 5, r = tid % 5;
    const float* W = (kind == 0) ? Wa : ((kind == 1) ? Wb : Ws);
    float v = 0.0f;
    for (int d = 0; d < 128; d++) v += sd[d] * W[d * 5 + r];
    v += (kind == 0) ? ba[r] : ((kind == 1) ? bb_[r] : bs[r]);
    if (kind == 2) v = 5.0f / (1.0f + __expf(-v));
    coeff[bb * 16 + kind * 5 + r] = v;
    return;
  }
  const int wave = tid >> 6, lane = tid & 63;
  const int wm = (wave >> 1) * 64, wn = (wave & 1) * 64;
  f32x4 acc[4][4];
#pragma unroll
  for (int i = 0; i < 4; i++)
#pragma unroll
    for (int j = 0; j < 4; j++)
#pragma unroll
      for (int r = 0; r < 4; r++) acc[i][j][r] = 0.0f;
  const int swz_rd = ((lane >> 4) ^ ((lane >> 1) & 3)) * 16;
  const int a_off = (wm + (lane & 15)) * 64 + swz_rd;
  const int b_off = (wn + (lane & 15)) * 64 + swz_rd;
  const int srow = wave * 32 + (lane >> 2);
  const int scol = ((lane & 3) ^ ((lane >> 3) & 3)) * 8;
  const u16* Asrc = xT + (long)bb * 524288 + ks * 512 + scol;
  const u16* Bsrc = UTr + (long)bb * 16777216 + (long)tn * 524288 + ks * 512 + scol;

  auto STAGE = [&](int k0, int buf) {
    char* dA = (char*)As + buf * 8192 + wave * 2048;
    char* dB = (char*)Bs + buf * 8192 + wave * 2048;
    gl_lds16(Asrc + (long)srow * 4096 + k0, dA);
    gl_lds16(Asrc + (long)(srow + 16) * 4096 + k0, dA + 1024);
    gl_lds16(Bsrc + (long)srow * 4096 + k0, dB);
    gl_lds16(Bsrc + (long)(srow + 16) * 4096 + k0, dB + 1024);
  };
  auto COMPUTE = [&](int buf) {
    bf16x8 af[4], bfr[4];
    const char* Ab_ = (const char*)As + buf * 8192 + a_off;
    const char* Bb_ = (const char*)Bs + buf * 8192 + b_off;
#pragma unroll
    for (int mt = 0; mt < 4; mt++) af[mt] = *(const bf16x8*)(Ab_ + mt * 1024);
#pragma unroll
    for (int nt = 0; nt < 4; nt++) bfr[nt] = *(const bf16x8*)(Bb_ + nt * 1024);
#pragma unroll
    for (int mt = 0; mt < 4; mt++)
#pragma unroll
      for (int nt = 0; nt < 4; nt++)
        acc[mt][nt] = __builtin_amdgcn_mfma_f32_16x16x32_bf16(af[mt], bfr[nt], acc[mt][nt], 0, 0, 0);
  };

  STAGE(0, 0);
  STAGE(32, 1);
  STAGE(64, 2);
  asm volatile("s_waitcnt vmcnt(8)" ::: "memory");
  __builtin_amdgcn_s_barrier();
  __builtin_amdgcn_sched_barrier(0);
#pragma unroll
  for (int t = 0; t < 13; ++t) {
    STAGE((t + 3) * 32, (t + 3) & 3);
    COMPUTE(t & 3);
    asm volatile("s_waitcnt vmcnt(8)" ::: "memory");
    __builtin_amdgcn_s_barrier();
    __builtin_amdgcn_sched_barrier(0);
  }
  COMPUTE(1);  // t = 13
  asm volatile("s_waitcnt vmcnt(4)" ::: "memory");
  __builtin_amdgcn_s_barrier();
  __builtin_amdgcn_sched_barrier(0);
  COMPUTE(2);  // t = 14
  asm volatile("s_waitcnt vmcnt(0)" ::: "memory");
  __builtin_amdgcn_s_barrier();
  __builtin_amdgcn_sched_barrier(0);
  COMPUTE(3);  // t = 15

  // transposed fp32 slice store: xs[ks][b][n][d]
  const int lr = (lane >> 4) * 4, lc = lane & 15;
  float* Cf = xs + (long)bb * 524288 + (long)ks * 1048576;
#pragma unroll
  for (int mt = 0; mt < 4; mt++)
#pragma unroll
    for (int nt = 0; nt < 4; nt++) {
      const int col = tn * 128 + wn + nt * 16 + lc;
#pragma unroll
      for (int r = 0; r < 4; r++) {
        const int row = wm + mt * 16 + lr + r;
        Cf[(long)col * 128 + row] = acc[mt][nt][r];
      }
    }
}

// ---- reduce 8 split-K slices, Chebyshev filters -> Mod bf16
__global__ void k_filter(const float* __restrict__ eig, const float* __restrict__ xs,
                         const float* __restrict__ coeff, u16* __restrict__ Mod) {
  const int b = blockIdx.y;
  const int n = blockIdx.x * 2 + (threadIdx.x >> 7);
  const int d = threadIdx.x & 127;
  const long ridx = (long)b * 4096 + n;
  const long off = ridx * 128 + d;
  const float e = eig[off];
  float xv = 0.0f;
#pragma unroll
  for (int s = 0; s < 8; s++) xv += xs[off + (long)s * 1048576];
  const float* cf = coeff + b * 16;
  float To = 1.0f, Tev = e;
  float h = cf[5];
#pragma unroll
  for (int i = 1; i < 5; i++) {
    To = 2.0f * e * Tev - To;
    Tev = 2.0f * e * To - Tev;
    h += cf[5 + i] * To;
  }
  u16* row = Mod + ridx * 768;
  row[d] = f2bf(h * xv);
#pragma unroll
  for (int j = 0; j < 5; j++) {
    const float sx = cf[10 + j] * e;
    float To2 = 1.0f, Te2 = sx;
    float g = cf[0] * Te2;
#pragma unroll
    for (int i = 1; i < 5; i++) {
      To2 = 2.0f * sx * Te2 - To2;
      Te2 = 2.0f * sx * To2 - Te2;
      g += cf[i] * Te2;
    }
    row[(j + 1) * 128 + d] = f2bf(g * xv);
  }
}

// ---- GEMM2: wT[e][m] = sum_k VT[e][k] Mod[m][k]; K=768, bf16 out
__global__ __launch_bounds__(256) void k_gemm2(
    const u16* __restrict__ VT, const u16* __restrict__ Mod, u16* __restrict__ wT) {
  const int tn = blockIdx.x, bb = blockIdx.z;
  __shared__ __align__(16) u16 As[4 * 4096];
  __shared__ __align__(16) u16 Bs[4 * 4096];
  const int tid = threadIdx.x, wave = tid >> 6, lane = tid & 63;
  const int wm = (wave >> 1) * 64, wn = (wave & 1) * 64;
  f32x4 acc[4][4];
#pragma unroll
  for (int i = 0; i < 4; i++)
#pragma unroll
    for (int j = 0; j < 4; j++)
#pragma unroll
      for (int r = 0; r < 4; r++) acc[i][j][r] = 0.0f;
  const int swz_rd = ((lane >> 4) ^ ((lane >> 1) & 3)) * 16;
  const int a_off = (wm + (lane & 15)) * 64 + swz_rd;
  const int b_off = (wn + (lane & 15)) * 64 + swz_rd;
  const int srow = wave * 32 + (lane >> 2);
  const int scol = ((lane & 3) ^ ((lane >> 3) & 3)) * 8;
  const u16* Asrc = VT + scol;
  const u16* Bsrc = Mod + (long)bb * 3145728 + (long)tn * 98304 + scol;

  auto STAGE = [&](int k0, int buf) {
    char* dA = (char*)As + buf * 8192 + wave * 2048;
    char* dB = (char*)Bs + buf * 8192 + wave * 2048;
    gl_lds16(Asrc + (long)srow * 768 + k0, dA);
    gl_lds16(Asrc + (long)(srow + 16) * 768 + k0, dA + 1024);
    gl_lds16(Bsrc + (long)srow * 768 + k0, dB);
    gl_lds16(Bsrc + (long)(srow + 16) * 768 + k0, dB + 1024);
  };
  auto COMPUTE = [&](int buf) {
    bf16x8 af[4], bfr[4];
    const char* Ab_ = (const char*)As + buf * 8192 + a_off;
    const char* Bb_ = (const char*)Bs + buf * 8192 + b_off;
#pragma unroll
    for (int mt = 0; mt < 4; mt++) af[mt] = *(const bf16x8*)(Ab_ + mt * 1024);
#pragma unroll
    for (int nt = 0; nt < 4; nt++) bfr[nt] = *(const bf16x8*)(Bb_ + nt * 1024);
#pragma unroll
    for (int mt = 0; mt < 4; mt++)
#pragma unroll
      for (int nt = 0; nt < 4; nt++)
        acc[mt][nt] = __builtin_amdgcn_mfma_f32_16x16x32_bf16(af[mt], bfr[nt], acc[mt][nt], 0, 0, 0);
  };

  STAGE(0, 0);
  STAGE(32, 1);
  STAGE(64, 2);
  asm volatile("s_waitcnt vmcnt(8)" ::: "memory");
  __builtin_amdgcn_s_barrier();
  __builtin_amdgcn_sched_barrier(0);
#pragma unroll
  for (int t = 0; t < 21; ++t) {
    STAGE((t + 3) * 32, (t + 3) & 3);
    COMPUTE(t & 3);
    asm volatile("s_waitcnt vmcnt(8)" ::: "memory");
    __builtin_amdgcn_s_barrier();
    __builtin_amdgcn_sched_barrier(0);
  }
  COMPUTE(1);  // t = 21
  asm volatile("s_waitcnt vmcnt(4)" ::: "memory");
  __builtin_amdgcn_s_barrier();
  __builtin_amdgcn_sched_barrier(0);
  COMPUTE(2);  // t = 22
  asm volatile("s_waitcnt vmcnt(0)" ::: "memory");
  __builtin_amdgcn_s_barrier();
  __builtin_amdgcn_sched_barrier(0);
  COMPUTE(3);  // t = 23

  const int lr = (lane >> 4) * 4, lc = lane & 15;
  u16* Cb = wT + (long)bb * 524288;
#pragma unroll
  for (int mt = 0; mt < 4; mt++)
#pragma unroll
    for (int nt = 0; nt < 4; nt++) {
      const int col = tn * 128 + wn + nt * 16 + lc;
#pragma unroll
      for (int r = 0; r < 4; r++) {
        const int row = wm + mt * 16 + lr + r;
        Cb[(long)row * 4096 + col] = f2bf(acc[mt][nt][r]);
      }
    }
}

// ---- GEMM3: os16[ks][b][n][e] = bf16 partial sum_m U[n][m] wT[e][m]
// A = Ubf bf16 [n][m]; B = wT bf16 [e][m].
__global__ __launch_bounds__(256) void k_gemm3(
    const u16* __restrict__ Ubf, const u16* __restrict__ wT, u16* __restrict__ os16) {
  const int tm = blockIdx.x, ks = blockIdx.y, bb = blockIdx.z;
  __shared__ __align__(16) u16 As[4 * 4096];
  __shared__ __align__(16) u16 Bs[4 * 4096];
  const int tid = threadIdx.x, wave = tid >> 6, lane = tid & 63;
  const int wm = (wave >> 1) * 64, wn = (wave & 1) * 64;
  f32x4 acc[4][4];
#pragma unroll
  for (int i = 0; i < 4; i++)
#pragma unroll
    for (int j = 0; j < 4; j++)
#pragma unroll
      for (int r = 0; r < 4; r++) acc[i][j][r] = 0.0f;
  const int swz_rd = ((lane >> 4) ^ ((lane >> 1) & 3)) * 16;
  const int a_off = (wm + (lane & 15)) * 64 + swz_rd;
  const int b_off = (wn + (lane & 15)) * 64 + swz_rd;
  const int srow = wave * 32 + (lane >> 2);
  const int scol = ((lane & 3) ^ ((lane >> 3) & 3)) * 8;
  const u16* Asrc = Ubf + (long)bb * 16777216 + (long)tm * 524288 + ks * 512 + scol;
  const u16* Bsrc = wT + (long)bb * 524288 + ks * 512 + scol;

  auto STAGE = [&](int k0, int buf) {
    char* dA = (char*)As + buf * 8192 + wave * 2048;
    char* dB = (char*)Bs + buf * 8192 + wave * 2048;
    gl_lds16(Asrc + (long)srow * 4096 + k0, dA);
    gl_lds16(Asrc + (long)(srow + 16) * 4096 + k0, dA + 1024);
    gl_lds16(Bsrc + (long)srow * 4096 + k0, dB);
    gl_lds16(Bsrc + (long)(srow + 16) * 4096 + k0, dB + 1024);
  };
  auto COMPUTE = [&](int buf) {
    bf16x8 af[4], bfr[4];
    const char* Ab_ = (const char*)As + buf * 8192 + a_off;
    const char* Bb_ = (const char*)Bs + buf * 8192 + b_off;
#pragma unroll
    for (int mt = 0; mt < 4; mt++) af[mt] = *(const bf16x8*)(Ab_ + mt * 1024);
#pragma unroll
    for (int nt = 0; nt < 4; nt++) bfr[nt] = *(const bf16x8*)(Bb_ + nt * 1024);
#pragma unroll
    for (int mt = 0; mt < 4; mt++)
#pragma unroll
      for (int nt = 0; nt < 4; nt++)
        acc[mt][nt] = __builtin_amdgcn_mfma_f32_16x16x32_bf16(af[mt], bfr[nt], acc[mt][nt], 0, 0, 0);
  };

  STAGE(0, 0);
  STAGE(32, 1);
  STAGE(64, 2);
  asm volatile("s_waitcnt vmcnt(8)" ::: "memory");
  __builtin_amdgcn_s_barrier();
  __builtin_amdgcn_sched_barrier(0);
#pragma unroll
  for (int t = 0; t < 13; ++t) {
    STAGE((t + 3) * 32, (t + 3) & 3);
    COMPUTE(t & 3);
    asm volatile("s_waitcnt vmcnt(8)" ::: "memory");
    __builtin_amdgcn_s_barrier();
    __builtin_amdgcn_sched_barrier(0);
  }
  COMPUTE(1);  // t = 13
  asm volatile("s_waitcnt vmcnt(4)" ::: "memory");
  __builtin_amdgcn_s_barrier();
  __builtin_amdgcn_sched_barrier(0);
  COMPUTE(2);  // t = 14
  asm volatile("s_waitcnt vmcnt(0)" ::: "memory");
  __builtin_amdgcn_s_barrier();
  __builtin_amdgcn_sched_barrier(0);
  COMPUTE(3);  // t = 15

  const int lr = (lane >> 4) * 4, lc = lane & 15;
  // slice layout: [ks][bb][n][e] — ks stride 1,048,576 elems, bb stride 524,288 elems
  u16* Cb = os16 + (long)ks * 1048576 + (long)bb * 524288;
#pragma unroll
  for (int mt = 0; mt < 4; mt++)
#pragma unroll
    for (int nt = 0; nt < 4; nt++) {
      const int col = wn + nt * 16 + lc;
#pragma unroll
      for (int r = 0; r < 4; r++) {
        const int row = tm * 128 + wm + mt * 16 + lr + r;
        Cb[(long)row * 128 + col] = f2bf(acc[mt][nt][r]);
      }
    }
}

// ---- out = sum of 8 bf16 slices + cvec
__global__ void k_outred(const u16* __restrict__ os16, const float* __restrict__ cvec,
                         float* __restrict__ out) {
  const long i = (long)blockIdx.x * 256 + threadIdx.x;
  const long j4 = i * 4;
  float4 r = {0.0f, 0.0f, 0.0f, 0.0f};
#pragma unroll
  for (int s = 0; s < 8; s++) {
    const uint2 v = *(const uint2*)(os16 + j4 + (long)s * 1048576);
    r.x += bf2f((u16)(v.x & 0xffff));
    r.y += bf2f((u16)(v.x >> 16));
    r.z += bf2f((u16)(v.y & 0xffff));
    r.w += bf2f((u16)(v.y >> 16));
  }
  const float4 cv = *(const float4*)(cvec + (i & 31) * 4);
  r.x += cv.x; r.y += cv.y; r.z += cv.z; r.w += cv.w;
  *(float4*)(out + j4) = r;
}

extern "C" void kernel_launch(void* const* d_in, const int* in_sizes, int n_in,
                              void* d_out, int out_size, void* d_ws, size_t ws_size,
                              hipStream_t stream) {
  const float* eig = (const float*)d_in[0];
  const float* x   = (const float*)d_in[1];
  const float* U   = (const float*)d_in[2];
  const float* Wa  = (const float*)d_in[3];
  const float* ba  = (const float*)d_in[4];
  const float* Wb  = (const float*)d_in[5];
  const float* bb  = (const float*)d_in[6];
  const float* Ws  = (const float*)d_in[7];
  const float* bs  = (const float*)d_in[8];
  const float* WSm = (const float*)d_in[9];
  const float* bS  = (const float*)d_in[10];
  const float* WM  = (const float*)d_in[11];
  const float* bM  = (const float*)d_in[12];
  const float* Ww  = (const float*)d_in[13];
  const float* bw  = (const float*)d_in[14];

  char* ws = (char*)d_ws;
  float* xs   = (float*)(ws + 0);          // 33,554,432 B (8 fp32 split-K slices)
  u16*   os16 = (u16*)(ws + 0);            // 16,777,216 B — aliases xs (xs dead after filter)
  u16*   Mod  = (u16*)(ws + 33554432);     // 12,582,912 B
  u16*   xT   = (u16*)(ws + 46137344);     //  2,097,152 B
  u16*   wT   = (u16*)(ws + 48234496);     //  2,097,152 B
  u16*   VT   = (u16*)(ws + 50331648);     //    196,608 B
  float* part = (float*)(ws + 50528256);   //     32,768 B
  float* coef = (float*)(ws + 50561024);   //        128 B
  float* cvec = (float*)(ws + 50561152);   //        512 B
  u16*   Ubf  = (u16*)(ws + 52428800);     // 67,108,864 B (U bf16, natural)
  u16*   UTr  = (u16*)(ws + 119537664);    // 67,108,864 B (U bf16, transposed)
  float* outp = (float*)d_out;

  if (ws_size < (size_t)186646528) return;  // workspace guard

  // prolog: eig means + x transpose + VT fold + cvec + U bf16 dual-copy
  k_pre<<<2753, 256, 0, stream>>>(eig, x, U, WSm, WM, Ww, bS, bM, bw,
                                  part, xT, VT, cvec, Ubf, UTr);

  // GEMM1 (+ pooled coefficients in tn==32 blocks)
  k_gemm1<<<dim3(33, 8, 2), 256, 0, stream>>>(xT, UTr, part, Wa, ba, Wb, bb, Ws, bs, xs, coef);

  // slice reduce + Chebyshev filters -> Mod bf16
  k_filter<<<dim3(2048, 2), 256, 0, stream>>>(eig, xs, coef, Mod);

  // GEMM2
  k_gemm2<<<dim3(32, 1, 2), 256, 0, stream>>>(VT, Mod, wT);

  // GEMM3 -> bf16 slices
  k_gemm3<<<dim3(32, 8, 2), 256, 0, stream>>>(Ubf, wT, os16);

  // final reduce + bias
  k_outred<<<1024, 256, 0, stream>>>(os16, cvec, outp);
}

// Round 6
// 293.754 us; speedup vs baseline: 1.1357x; 1.1357x over previous
//
#include <hip/hip_runtime.h>
#include <hip/hip_bf16.h>
#include <stdint.h>

typedef unsigned short u16;
typedef __attribute__((ext_vector_type(8))) short bf16x8;
typedef __attribute__((ext_vector_type(4))) float f32x4;
typedef __attribute__((ext_vector_type(4))) uint32_t u32x4;

__device__ inline u16 f2bf(float f) {
  union { float f; uint32_t u; } v; v.f = f;
  uint32_t u = v.u;
  u += 0x7FFFu + ((u >> 16) & 1u);
  return (u16)(u >> 16);
}
__device__ inline uint32_t pkbf(float a, float b) {
  union { __hip_bfloat162 h; uint32_t u; } c;
  c.h = __float22bfloat162_rn(float2{a, b});
  return c.u;
}
__device__ inline float bf2f(u16 h) {
  union { uint32_t u; float f; } v; v.u = (uint32_t)h << 16; return v.f;
}
__device__ inline void gl_lds16(const void* g, void* s) {
  __builtin_amdgcn_global_load_lds(
      (const __attribute__((address_space(1))) void*)(uintptr_t)(g),
      (__attribute__((address_space(3))) void*)(uint32_t)(uintptr_t)(s),
      16, 0, 0);
}

// ---- prolog: eig partial means (0..63) + x transpose (64..319)
//      + VT weight fold (320..703) + cvec (704)
__global__ __launch_bounds__(256) void k_pre(
    const float* __restrict__ eig, const float* __restrict__ x,
    const float* __restrict__ WS, const float* __restrict__ WM,
    const float* __restrict__ Ww, const float* __restrict__ bS,
    const float* __restrict__ bM, const float* __restrict__ bw,
    float* __restrict__ part, u16* __restrict__ xT,
    u16* __restrict__ VT, float* __restrict__ cvec) {
  const int bid = blockIdx.x, t = threadIdx.x;
  __shared__ float red[256];
  __shared__ uint32_t L[64][33];
  if (bid < 64) {
    const int b = bid >> 5, chunk = bid & 31;
    const int d = t & 127, half = t >> 7;
    const float* p = eig + ((long)b * 4096 + chunk * 128 + half) * 128 + d;
    float s = 0.0f;
    for (int i = 0; i < 64; i++) s += p[(long)i * 256];
    red[t] = s;
    __syncthreads();
    if (t < 128) part[((long)b * 32 + chunk) * 128 + d] = red[t] + red[t + 128];
    return;
  }
  if (bid < 320) {
    // x fp32 [4096][128] -> xT bf16 [128][4096], 64x64 tiles
    const int q = bid - 64;
    const int b = q >> 7, rem = q & 127;
    const int tr = rem & 63, tc = rem >> 6;
    const float* I = x + (long)b * 524288;
    u16* O = xT + (long)b * 524288;
    const int r = t >> 2, cq = (t & 3) * 4;
    const float* src = I + (long)(tr * 64 + r) * 128 + tc * 64;
#pragma unroll
    for (int i = 0; i < 4; i++) {
      const float4 f = *(const float4*)(src + cq + 16 * i);
      const int c = cq + 16 * i;
      L[r][(c >> 1)]     = pkbf(f.x, f.y);
      L[r][(c >> 1) + 1] = pkbf(f.z, f.w);
    }
    __syncthreads();
    const int r0 = (t & 7) * 8;
#pragma unroll
    for (int p = 0; p < 2; p++) {
      const int c = (t >> 3) + 32 * p;
      uint32_t w[4];
#pragma unroll
      for (int i = 0; i < 4; i++) {
        const uint32_t w0 = L[r0 + 2 * i][c >> 1];
        const uint32_t w1 = L[r0 + 2 * i + 1][c >> 1];
        const u16 v0 = (c & 1) ? (u16)(w0 >> 16) : (u16)(w0 & 0xffff);
        const u16 v1 = (c & 1) ? (u16)(w1 >> 16) : (u16)(w1 & 0xffff);
        w[i] = (uint32_t)v0 | ((uint32_t)v1 << 16);
      }
      u32x4* dst = (u32x4*)(O + (long)(tc * 64 + c) * 4096 + tr * 64 + r0);
      *dst = u32x4{w[0], w[1], w[2], w[3]};
    }
    return;
  }
  if (bid < 704) {
    // VT[e][f*128+d] = (F_f @ Ww)[d][e]; 2 q per block
    const int q = (bid - 320) * 2 + (t >> 7);
    const int e = t & 127;
    const int f = q >> 7, d = q & 127;
    const float* Frow = (f == 0) ? (WS + d * 128) : (WM + ((long)(f - 1) * 128 + d) * 128);
    float s = 0.0f;
    for (int k = 0; k < 128; k++) s += Frow[k] * Ww[k * 128 + e];
    VT[(long)e * 768 + f * 128 + d] = f2bf(s);
    return;
  }
  // cvec
  if (t >= 128) return;
  float s = bw[t];
  for (int k = 0; k < 128; k++) {
    float tv = bS[k];
#pragma unroll
    for (int j = 0; j < 5; j++) tv += bM[j * 128 + k];
    s += tv * Ww[k * 128 + t];
  }
  cvec[t] = s;
}

// ---- GEMM1: xs[ks][b][n][d] = partial sum_m U[m][n] * x[m][d]
// A = xT bf16 [d][m] via gl_lds (swizzled source); B = U fp32 columns,
// 2-deep register prefetch -> transposed pad-17 LDS tile (conflict-free).
__global__ __launch_bounds__(256) void k_gemm1(
    const u16* __restrict__ xT, const float* __restrict__ U,
    const float* __restrict__ part,
    const float* __restrict__ Wa, const float* __restrict__ ba,
    const float* __restrict__ Wb, const float* __restrict__ bb_,
    const float* __restrict__ Ws, const float* __restrict__ bs,
    float* __restrict__ xs, float* __restrict__ coeff) {
  const int tn = blockIdx.x, ks = blockIdx.y, bb = blockIdx.z;
  const int tid = threadIdx.x;
  __shared__ float sd[128];
  __shared__ __align__(16) u16 As[2 * 128 * 32];        // 2 x 8192 B
  __shared__ __align__(16) uint32_t Bsw[2 * 128 * 17];  // 2 x 8704 B (pad-17)
  if (tn == 32) {
    if (ks != 0) return;
    if (tid < 128) {
      float s = 0.0f;
      for (int c = 0; c < 32; c++) s += part[((long)bb * 32 + c) * 128 + tid];
      sd[tid] = s * (1.0f / 4096.0f);
    }
    __syncthreads();
    if (tid >= 15) return;
    const int kind = tid / 5, r = tid % 5;
    const float* W = (kind == 0) ? Wa : ((kind == 1) ? Wb : Ws);
    float v = 0.0f;
    for (int d = 0; d < 128; d++) v += sd[d] * W[d * 5 + r];
    v += (kind == 0) ? ba[r] : ((kind == 1) ? bb_[r] : bs[r]);
    if (kind == 2) v = 5.0f / (1.0f + __expf(-v));
    coeff[bb * 16 + kind * 5 + r] = v;
    return;
  }
  const int wave = tid >> 6, lane = tid & 63;
  const int wm = (wave >> 1) * 64, wn = (wave & 1) * 64;
  f32x4 acc[4][4];
#pragma unroll
  for (int i = 0; i < 4; i++)
#pragma unroll
    for (int j = 0; j < 4; j++)
#pragma unroll
      for (int r = 0; r < 4; r++) acc[i][j][r] = 0.0f;
  // swizzled A read; padded B read (unchanged layout)
  const int a_off = (wm + (lane & 15)) * 64 + (((lane >> 4) ^ ((lane >> 1) & 3)) * 16);
  const int b_off = (wn + (lane & 15)) * 68 + (lane >> 4) * 16;
  // gl_lds staging (A): source k-chunk pre-swizzled
  const int srow = wave * 32 + (lane >> 2);
  const int scol_sw = ((lane & 3) ^ ((lane >> 3) & 3)) * 8;
  const u16* Ab = xT + (long)bb * 524288 + ks * 512;
  // B fp32 source
  const int q = tid & 15, cb = tid >> 4;
  const float* Bbase = U + (long)bb * 16777216 + tn * 128 + cb * 8;

#define G1_STAGEA(KO, BUF) do { \
    const u16* s_ = Ab + (KO) + scol_sw; \
    char* d_ = (char*)As + (BUF) * 8192 + wave * 2048; \
    gl_lds16(s_ + (long)srow * 4096, d_); \
    gl_lds16(s_ + (long)(srow + 16) * 4096, d_ + 1024); } while (0)

#define G1_LOADB(Pa0, Pa1, Pc0, Pc1, KO) do { \
    const float* r0_ = Bbase + (long)(ks * 512 + (KO) + 2 * q) * 4096; \
    Pa0 = *(const float4*)(r0_); Pa1 = *(const float4*)(r0_ + 4); \
    const float* r1_ = r0_ + 4096; \
    Pc0 = *(const float4*)(r1_); Pc1 = *(const float4*)(r1_ + 4); } while (0)

#define G1_WRITEB(Pa0, Pa1, Pc0, Pc1, BUF) do { \
    uint32_t* dw_ = Bsw + (BUF) * 2176 + (cb * 8) * 17 + q; \
    dw_[0]   = pkbf(Pa0.x, Pc0.x); dw_[17]  = pkbf(Pa0.y, Pc0.y); \
    dw_[34]  = pkbf(Pa0.z, Pc0.z); dw_[51]  = pkbf(Pa0.w, Pc0.w); \
    dw_[68]  = pkbf(Pa1.x, Pc1.x); dw_[85]  = pkbf(Pa1.y, Pc1.y); \
    dw_[102] = pkbf(Pa1.z, Pc1.z); dw_[119] = pkbf(Pa1.w, Pc1.w); } while (0)

#define G1_COMPUTE(BUF) do { \
    bf16x8 af[4], bfr[4]; \
    const char* Ab_ = (const char*)As + (BUF) * 8192 + a_off; \
    const char* Bb_ = (const char*)Bsw + (BUF) * 8704 + b_off; \
    _Pragma("unroll") for (int mt = 0; mt < 4; mt++) \
      af[mt] = *(const bf16x8*)(Ab_ + mt * 1024); \
    _Pragma("unroll") for (int nt = 0; nt < 4; nt++) \
      bfr[nt] = *(const bf16x8*)(Bb_ + nt * 1088); \
    _Pragma("unroll") for (int mt = 0; mt < 4; mt++) \
      _Pragma("unroll") for (int nt = 0; nt < 4; nt++) \
        acc[mt][nt] = __builtin_amdgcn_mfma_f32_16x16x32_bf16(af[mt], bfr[nt], acc[mt][nt], 0, 0, 0); } while (0)

  float4 pa0, pa1, pc0, pc1;  // set p
  float4 qa0, qa1, qc0, qc1;  // set q
  // prologue: tile0 A+B staged, tile1 B regs in flight
  G1_STAGEA(0, 0);
  G1_LOADB(pa0, pa1, pc0, pc1, 0);
  G1_LOADB(qa0, qa1, qc0, qc1, 32);
  G1_WRITEB(pa0, pa1, pc0, pc1, 0);
  asm volatile("s_waitcnt vmcnt(0) lgkmcnt(0)" ::: "memory");
  __builtin_amdgcn_s_barrier();
  __builtin_amdgcn_sched_barrier(0);
  for (int it = 0; it < 7; ++it) {
    const int k0 = it * 64;
    // t = 2it (compute buf0)
    G1_STAGEA(k0 + 32, 1);
    __builtin_amdgcn_sched_barrier(0);  // keep gl_lds older than reg loads
    G1_LOADB(pa0, pa1, pc0, pc1, k0 + 64);
    G1_COMPUTE(0);
    G1_WRITEB(qa0, qa1, qc0, qc1, 1);
    asm volatile("s_waitcnt vmcnt(4) lgkmcnt(0)" ::: "memory");
    __builtin_amdgcn_s_barrier();
    __builtin_amdgcn_sched_barrier(0);
    // t = 2it+1 (compute buf1)
    G1_STAGEA(k0 + 64, 0);
    __builtin_amdgcn_sched_barrier(0);
    G1_LOADB(qa0, qa1, qc0, qc1, k0 + 96);
    G1_COMPUTE(1);
    G1_WRITEB(pa0, pa1, pc0, pc1, 0);
    asm volatile("s_waitcnt vmcnt(4) lgkmcnt(0)" ::: "memory");
    __builtin_amdgcn_s_barrier();
    __builtin_amdgcn_sched_barrier(0);
  }
  // t = 14
  G1_STAGEA(480, 1);
  G1_COMPUTE(0);
  G1_WRITEB(qa0, qa1, qc0, qc1, 1);
  asm volatile("s_waitcnt vmcnt(0) lgkmcnt(0)" ::: "memory");
  __builtin_amdgcn_s_barrier();
  __builtin_amdgcn_sched_barrier(0);
  // t = 15
  G1_COMPUTE(1);
#undef G1_STAGEA
#undef G1_LOADB
#undef G1_WRITEB
#undef G1_COMPUTE
  // transposed fp32 slice store: xs[ks][b][n][d]
  const int lr = (lane >> 4) * 4, lc = lane & 15;
  float* Cf = xs + (long)bb * 524288 + (long)ks * 1048576;
#pragma unroll
  for (int mt = 0; mt < 4; mt++)
#pragma unroll
    for (int nt = 0; nt < 4; nt++) {
      const int col = tn * 128 + wn + nt * 16 + lc;
#pragma unroll
      for (int r = 0; r < 4; r++) {
        const int row = wm + mt * 16 + lr + r;
        Cf[(long)col * 128 + row] = acc[mt][nt][r];
      }
    }
}

// ---- reduce 8 split-K slices, Chebyshev filters -> Mod bf16
__global__ void k_filter(const float* __restrict__ eig, const float* __restrict__ xs,
                         const float* __restrict__ coeff, u16* __restrict__ Mod) {
  const int b = blockIdx.y;
  const int n = blockIdx.x * 2 + (threadIdx.x >> 7);
  const int d = threadIdx.x & 127;
  const long ridx = (long)b * 4096 + n;
  const long off = ridx * 128 + d;
  const float e = eig[off];
  float xv = 0.0f;
#pragma unroll
  for (int s = 0; s < 8; s++) xv += xs[off + (long)s * 1048576];
  const float* cf = coeff + b * 16;
  float To = 1.0f, Tev = e;
  float h = cf[5];
#pragma unroll
  for (int i = 1; i < 5; i++) {
    To = 2.0f * e * Tev - To;
    Tev = 2.0f * e * To - Tev;
    h += cf[5 + i] * To;
  }
  u16* row = Mod + ridx * 768;
  row[d] = f2bf(h * xv);
#pragma unroll
  for (int j = 0; j < 5; j++) {
    const float sx = cf[10 + j] * e;
    float To2 = 1.0f, Te2 = sx;
    float g = cf[0] * Te2;
#pragma unroll
    for (int i = 1; i < 5; i++) {
      To2 = 2.0f * sx * Te2 - To2;
      Te2 = 2.0f * sx * To2 - Te2;
      g += cf[i] * Te2;
    }
    row[(j + 1) * 128 + d] = f2bf(g * xv);
  }
}

// ---- GEMM2: wT[e][m] = sum_k VT[e][k] Mod[m][k]; K=768, bf16 out
// BN=64: grid (64,1,2) = 128 blocks (was 64 on 256 CUs = 25% occupancy).
// Same 2-buffer / vmcnt(0) structure and swizzle algebra as the proven
// BN=128 version; per-wave output 64x32 (acc 4x2); B stage = 1 gl_lds/wave.
__global__ __launch_bounds__(256) void k_gemm2(
    const u16* __restrict__ VT, const u16* __restrict__ Mod, u16* __restrict__ wT) {
  const int tn = blockIdx.x, bb = blockIdx.z;
  __shared__ __align__(16) u16 As[2 * 128 * 32];   // 2 x 8 KB
  __shared__ __align__(16) u16 Bs[2 * 64 * 32];    // 2 x 4 KB
  const int tid = threadIdx.x, wave = tid >> 6, lane = tid & 63;
  const int wm = (wave >> 1) * 64, wn = (wave & 1) * 32;
  f32x4 acc[4][2];
#pragma unroll
  for (int i = 0; i < 4; i++)
#pragma unroll
    for (int j = 0; j < 2; j++)
#pragma unroll
      for (int r = 0; r < 4; r++) acc[i][j][r] = 0.0f;
  const int swz_rd = ((lane >> 4) ^ ((lane >> 1) & 3)) * 16;
  const int a_off = (wm + (lane & 15)) * 64 + swz_rd;
  const int b_off = (wn + (lane & 15)) * 64 + swz_rd;
  const int srowA = wave * 32 + (lane >> 2);
  const int srowB = wave * 16 + (lane >> 2);
  const int scol = ((lane & 3) ^ ((lane >> 3) & 3)) * 8;
  const u16* Asrc = VT + scol;
  const u16* Bsrc = Mod + (long)bb * 3145728 + (long)tn * 49152 + scol;

  auto STAGE = [&](int k0, int buf) {
    char* dA = (char*)As + buf * 8192 + wave * 2048;
    char* dB = (char*)Bs + buf * 4096 + wave * 1024;
    gl_lds16(Asrc + (long)srowA * 768 + k0, dA);
    gl_lds16(Asrc + (long)(srowA + 16) * 768 + k0, dA + 1024);
    gl_lds16(Bsrc + (long)srowB * 768 + k0, dB);
  };
  auto COMPUTE = [&](int buf) {
    bf16x8 af[4], bfr[2];
    const char* Ab_ = (const char*)As + buf * 8192 + a_off;
    const char* Bb_ = (const char*)Bs + buf * 4096 + b_off;
#pragma unroll
    for (int mt = 0; mt < 4; mt++) af[mt] = *(const bf16x8*)(Ab_ + mt * 1024);
#pragma unroll
    for (int nt = 0; nt < 2; nt++) bfr[nt] = *(const bf16x8*)(Bb_ + nt * 1024);
#pragma unroll
    for (int mt = 0; mt < 4; mt++)
#pragma unroll
      for (int nt = 0; nt < 2; nt++)
        acc[mt][nt] = __builtin_amdgcn_mfma_f32_16x16x32_bf16(af[mt], bfr[nt], acc[mt][nt], 0, 0, 0);
  };

  STAGE(0, 0);
  asm volatile("s_waitcnt vmcnt(0)" ::: "memory");
  __builtin_amdgcn_s_barrier();
  __builtin_amdgcn_sched_barrier(0);
#pragma unroll
  for (int t = 0; t < 23; ++t) {
    STAGE((t + 1) * 32, (t + 1) & 1);
    COMPUTE(t & 1);
    asm volatile("s_waitcnt vmcnt(0) lgkmcnt(0)" ::: "memory");
    __builtin_amdgcn_s_barrier();
    __builtin_amdgcn_sched_barrier(0);
  }
  COMPUTE(1);  // t = 23

  const int lr = (lane >> 4) * 4, lc = lane & 15;
  u16* Cb = wT + (long)bb * 524288;
#pragma unroll
  for (int mt = 0; mt < 4; mt++)
#pragma unroll
    for (int nt = 0; nt < 2; nt++) {
      const int col = tn * 64 + wn + nt * 16 + lc;
#pragma unroll
      for (int r = 0; r < 4; r++) {
        const int row = wm + mt * 16 + lr + r;
        Cb[(long)row * 4096 + col] = f2bf(acc[mt][nt][r]);
      }
    }
}

// ---- GEMM3: os16[ks][b][n][e] = bf16 partial sum_m U[n][m] wT[e][m]
// A = U fp32 rows, 2-deep register prefetch -> swizzled ds_write;
// B = wT bf16 via gl_lds (swizzled source).
__global__ __launch_bounds__(256) void k_gemm3(
    const float* __restrict__ U, const u16* __restrict__ wT, u16* __restrict__ os16) {
  const int tm = blockIdx.x, ks = blockIdx.y, bb = blockIdx.z;
  __shared__ __align__(16) u16 As[2 * 128 * 32];
  __shared__ __align__(16) u16 Bs[2 * 128 * 32];
  const int tid = threadIdx.x, wave = tid >> 6, lane = tid & 63;
  const int wm = (wave >> 1) * 64, wn = (wave & 1) * 64;
  f32x4 acc[4][4];
#pragma unroll
  for (int i = 0; i < 4; i++)
#pragma unroll
    for (int j = 0; j < 4; j++)
#pragma unroll
      for (int r = 0; r < 4; r++) acc[i][j][r] = 0.0f;
  const int rd_swz = ((lane >> 4) ^ ((lane >> 1) & 3)) * 16;
  const int a_off = (wm + (lane & 15)) * 64 + rd_swz;
  const int b_off = (wn + (lane & 15)) * 64 + rd_swz;
  const int srow = wave * 32 + (lane >> 2);
  const int scol_sw = ((lane & 3) ^ ((lane >> 3) & 3)) * 8;
  const int wslot = ((tid & 3) ^ ((tid >> 3) & 3));  // ds_write slot swizzle
  const float* Abase = U + (long)bb * 16777216 +
                       (long)(tm * 128 + (tid >> 2)) * 4096 + (tid & 3) * 8;
  const u16* Bb = wT + (long)bb * 524288 + ks * 512;

#define G3_STAGEB(KO, BUF) do { \
    const u16* s_ = Bb + (KO) + scol_sw; \
    char* d_ = (char*)Bs + (BUF) * 8192 + wave * 2048; \
    gl_lds16(s_ + (long)srow * 4096, d_); \
    gl_lds16(s_ + (long)(srow + 16) * 4096, d_ + 1024); } while (0)

#define G3_LOADA(Pf0, Pf1, Pg0, Pg1, KO) do { \
    const float* s0_ = Abase + ks * 512 + (KO); \
    Pf0 = *(const float4*)(s0_); Pf1 = *(const float4*)(s0_ + 4); \
    const float* s1_ = s0_ + 262144; \
    Pg0 = *(const float4*)(s1_); Pg1 = *(const float4*)(s1_ + 4); } while (0)

#define G3_WRITEA(Pf0, Pf1, Pg0, Pg1, BUF) do { \
    char* d_ = (char*)As + (BUF) * 8192 + (tid >> 2) * 64 + wslot * 16; \
    *(u32x4*)(d_) = u32x4{pkbf(Pf0.x, Pf0.y), pkbf(Pf0.z, Pf0.w), \
                          pkbf(Pf1.x, Pf1.y), pkbf(Pf1.z, Pf1.w)}; \
    *(u32x4*)(d_ + 4096) = u32x4{pkbf(Pg0.x, Pg0.y), pkbf(Pg0.z, Pg0.w), \
                                 pkbf(Pg1.x, Pg1.y), pkbf(Pg1.z, Pg1.w)}; } while (0)

#define G3_COMPUTE(BUF) do { \
    bf16x8 af[4], bfr[4]; \
    const char* Ab_ = (const char*)As + (BUF) * 8192 + a_off; \
    const char* Bb_ = (const char*)Bs + (BUF) * 8192 + b_off; \
    _Pragma("unroll") for (int mt = 0; mt < 4; mt++) \
      af[mt] = *(const bf16x8*)(Ab_ + mt * 1024); \
    _Pragma("unroll") for (int nt = 0; nt < 4; nt++) \
      bfr[nt] = *(const bf16x8*)(Bb_ + nt * 1024); \
    _Pragma("unroll") for (int mt = 0; mt < 4; mt++) \
      _Pragma("unroll") for (int nt = 0; nt < 4; nt++) \
        acc[mt][nt] = __builtin_amdgcn_mfma_f32_16x16x32_bf16(af[mt], bfr[nt], acc[mt][nt], 0, 0, 0); } while (0)

  float4 pf0, pf1, pg0, pg1;  // set p
  float4 qf0, qf1, qg0, qg1;  // set q
  G3_STAGEB(0, 0);
  G3_LOADA(pf0, pf1, pg0, pg1, 0);
  G3_LOADA(qf0, qf1, qg0, qg1, 32);
  G3_WRITEA(pf0, pf1, pg0, pg1, 0);
  asm volatile("s_waitcnt vmcnt(0) lgkmcnt(0)" ::: "memory");
  __builtin_amdgcn_s_barrier();
  __builtin_amdgcn_sched_barrier(0);
  for (int it = 0; it < 7; ++it) {
    const int k0 = it * 64;
    // t = 2it (compute buf0)
    G3_STAGEB(k0 + 32, 1);
    __builtin_amdgcn_sched_barrier(0);
    G3_LOADA(pf0, pf1, pg0, pg1, k0 + 64);
    G3_COMPUTE(0);
    G3_WRITEA(qf0, qf1, qg0, qg1, 1);
    asm volatile("s_waitcnt vmcnt(4) lgkmcnt(0)" ::: "memory");
    __builtin_amdgcn_s_barrier();
    __builtin_amdgcn_sched_barrier(0);
    // t = 2it+1 (compute buf1)
    G3_STAGEB(k0 + 64, 0);
    __builtin_amdgcn_sched_barrier(0);
    G3_LOADA(qf0, qf1, qg0, qg1, k0 + 96);
    G3_COMPUTE(1);
    G3_WRITEA(pf0, pf1, pg0, pg1, 0);
    asm volatile("s_waitcnt vmcnt(4) lgkmcnt(0)" ::: "memory");
    __builtin_amdgcn_s_barrier();
    __builtin_amdgcn_sched_barrier(0);
  }
  // t = 14
  G3_STAGEB(480, 1);
  G3_COMPUTE(0);
  G3_WRITEA(qf0, qf1, qg0, qg1, 1);
  asm volatile("s_waitcnt vmcnt(0) lgkmcnt(0)" ::: "memory");
  __builtin_amdgcn_s_barrier();
  __builtin_amdgcn_sched_barrier(0);
  // t = 15
  G3_COMPUTE(1);
#undef G3_STAGEB
#undef G3_LOADA
#undef G3_WRITEA
#undef G3_COMPUTE
  const int lr = (lane >> 4) * 4, lc = lane & 15;
  // slice layout: [ks][bb][n][e] — ks stride 1,048,576 elems, bb stride 524,288 elems
  u16* Cb = os16 + (long)ks * 1048576 + (long)bb * 524288;
#pragma unroll
  for (int mt = 0; mt < 4; mt++)
#pragma unroll
    for (int nt = 0; nt < 4; nt++) {
      const int col = wn + nt * 16 + lc;
#pragma unroll
      for (int r = 0; r < 4; r++) {
        const int row = tm * 128 + wm + mt * 16 + lr + r;
        Cb[(long)row * 128 + col] = f2bf(acc[mt][nt][r]);
      }
    }
}

// ---- out = sum of 8 bf16 slices + cvec
__global__ void k_outred(const u16* __restrict__ os16, const float* __restrict__ cvec,
                         float* __restrict__ out) {
  const long i = (long)blockIdx.x * 256 + threadIdx.x;
  const long j4 = i * 4;
  float4 r = {0.0f, 0.0f, 0.0f, 0.0f};
#pragma unroll
  for (int s = 0; s < 8; s++) {
    const uint2 v = *(const uint2*)(os16 + j4 + (long)s * 1048576);
    r.x += bf2f((u16)(v.x & 0xffff));
    r.y += bf2f((u16)(v.x >> 16));
    r.z += bf2f((u16)(v.y & 0xffff));
    r.w += bf2f((u16)(v.y >> 16));
  }
  const float4 cv = *(const float4*)(cvec + (i & 31) * 4);
  r.x += cv.x; r.y += cv.y; r.z += cv.z; r.w += cv.w;
  *(float4*)(out + j4) = r;
}

extern "C" void kernel_launch(void* const* d_in, const int* in_sizes, int n_in,
                              void* d_out, int out_size, void* d_ws, size_t ws_size,
                              hipStream_t stream) {
  const float* eig = (const float*)d_in[0];
  const float* x   = (const float*)d_in[1];
  const float* U   = (const float*)d_in[2];
  const float* Wa  = (const float*)d_in[3];
  const float* ba  = (const float*)d_in[4];
  const float* Wb  = (const float*)d_in[5];
  const float* bb  = (const float*)d_in[6];
  const float* Ws  = (const float*)d_in[7];
  const float* bs  = (const float*)d_in[8];
  const float* WSm = (const float*)d_in[9];
  const float* bS  = (const float*)d_in[10];
  const float* WM  = (const float*)d_in[11];
  const float* bM  = (const float*)d_in[12];
  const float* Ww  = (const float*)d_in[13];
  const float* bw  = (const float*)d_in[14];

  char* ws = (char*)d_ws;
  float* xs   = (float*)(ws + 0);          // 33,554,432 B (8 fp32 split-K slices)
  u16*   os16 = (u16*)(ws + 0);            // 16,777,216 B — aliases xs (xs dead after filter)
  u16*   Mod  = (u16*)(ws + 33554432);     // 12,582,912 B
  u16*   xT   = (u16*)(ws + 46137344);     //  2,097,152 B
  u16*   wT   = (u16*)(ws + 48234496);     //  2,097,152 B
  u16*   VT   = (u16*)(ws + 50331648);     //    196,608 B
  float* part = (float*)(ws + 50528256);   //     32,768 B
  float* coef = (float*)(ws + 50561024);   //        128 B
  float* cvec = (float*)(ws + 50561152);   //        512 B
  float* outp = (float*)d_out;

  if (ws_size < (size_t)50561664) return;  // workspace guard

  // prolog: eig means + x transpose + VT fold + cvec (one launch)
  k_pre<<<705, 256, 0, stream>>>(eig, x, WSm, WM, Ww, bS, bM, bw, part, xT, VT, cvec);

  // GEMM1 (+ pooled coefficients in tn==32 blocks)
  k_gemm1<<<dim3(33, 8, 2), 256, 0, stream>>>(xT, U, part, Wa, ba, Wb, bb, Ws, bs, xs, coef);

  // slice reduce + Chebyshev filters -> Mod bf16
  k_filter<<<dim3(2048, 2), 256, 0, stream>>>(eig, xs, coef, Mod);

  // GEMM2 (BN=64 -> 128 blocks)
  k_gemm2<<<dim3(64, 1, 2), 256, 0, stream>>>(VT, Mod, wT);

  // GEMM3 -> bf16 slices
  k_gemm3<<<dim3(32, 8, 2), 256, 0, stream>>>(U, wT, os16);

  // final reduce + bias
  k_outred<<<1024, 256, 0, stream>>>(os16, cvec, outp);
}